// Round 18
// baseline (57.908 us; speedup 1.0000x reference)
//
#include <hip/hip_runtime.h>
#include <math.h>

#define BB 2
#define CC 2
#define DD 64
#define HW 65536
#define NROW 128
#define EPSF 1e-6f
#define ALPHAF 5.0f
#define LOG2E 1.44269504089f
#define LN2 0.69314718056f
#define INV_T (1.0f/0.7f)
#define C_SH (INV_T*LOG2E)

// R16 lesson: spin-handshakes serialize (like R2's atomics) -- dead axis.
// R17: scan-once via separate kernel (plain stores), body at 2 blocks/CU
// (8 waves/SIMD, zero added bytes), k_final fused via last-block retirement
// (completion count -- no spinning, no co-residency assumption).
// Fabric ledger: scan 33.5 + body 134 = 167.5 MB (was 201).
struct Ws {
  int   done;                 // MUST be first: 4-byte memsetAsync per launch
  int   scanp[NROW][2][6];    // per-half partials: cnt0,ys0,xs0,cnt1,ys1,xs1
  float tgt[2][NROW][2];
  float valid[2][NROW];
  float part[NROW][4][17];
  // 0 denom0 1 ynum0 2 xnum0 | 3 denom1 4 ynum1 5 xnum1 | 6 P0 7 P1
  // 8 SluOut0 9 SowOut0 10 SluIn0 11 SowIn0 | 12..15 same k=1 | 16 csis
};

// ---------------- kernel 1: label scan, block = (row, half-plane) -----------
__global__ __launch_bounds__(1024) void k_scan(const int* __restrict__ cl,
                                               Ws* __restrict__ ws) {
  const int row  = blockIdx.x >> 1;
  const int half = blockIdx.x & 1;
  const int tid  = threadIdx.x;
  __shared__ int sacc[6];
  if (tid < 6) sacc[tid] = 0;
  __syncthreads();
  const int4* cp = (const int4*)(cl + ((long long)row << 16) + (half << 15));
#pragma unroll 8
  for (int j = 0; j < 8; ++j) {
    const int idx4 = tid + (j << 10);
    const int4 v = cp[idx4];
    if ((v.x | v.y | v.z | v.w) != 0) {
      const int vv[4] = {v.x, v.y, v.z, v.w};
#pragma unroll
      for (int e = 0; e < 4; ++e) {
        const int val = vv[e];
        if (val == 1 || val == 2) {
          const int hw = (half << 15) + (idx4 << 2) + e;
          const int k3 = (val - 1) * 3;
          atomicAdd(&sacc[k3 + 0], 1);
          atomicAdd(&sacc[k3 + 1], hw >> 8);
          atomicAdd(&sacc[k3 + 2], hw & 255);
        }
      }
    }
  }
  __syncthreads();
  if (tid < 6) ws->scanp[row][half][tid] = sacc[tid];
}

// ---------------- row body ---------------------------------------------------
struct RowCtx {
  float t0y, t0x, t1y, t1x;   // target minus EPSF (so diff = g - t + EPS)
  float r01sq, r11sq;
  float c00, c01, c10, c11;   // LOG2E / r
};

// N0/N1: row within ring range of target0/1. Far: relu(1-exp(1-d/r))==1
// (err<=e^-5, validated absmax 0.0), relu(exp-1)==0, art==1 exactly.
// acc[16]=csis product sum (psig_own * delta_next), acc[17]=softplus_own sum.
template<bool N0, bool N1>
__device__ __forceinline__ void do_row(const float4& v0, const float4& v1,
                                       const float4& w0, const float4& w1,
                                       float yf, float x0f,
                                       const RowCtx& cx, float* acc)
{
  const float a0[4] = {v0.x, v0.y, v0.z, v0.w};
  const float a1[4] = {v1.x, v1.y, v1.z, v1.w};
  const float b0[4] = {w0.x, w0.y, w0.z, w0.w};
  const float b1[4] = {w1.x, w1.y, w1.z, w1.w};
  float rp0 = 0.f, rp1 = 0.f, rprod = 0.f, rsp = 0.f, rpsx = 0.f;
  float rA0 = 0.f, rA0x = 0.f, rT00 = 0.f, rT01 = 0.f;
  float rA1 = 0.f, rA1x = 0.f, rT10 = 0.f, rT11 = 0.f;
  const float dy0 = yf - cx.t0y;
  const float dy0sq = dy0 * dy0;
  const float dy1 = yf - cx.t1y;
  const float dy1sq = dy1 * dy1;
#pragma unroll
  for (int e = 0; e < 4; ++e) {
    const float le0 = a0[e], le1 = a1[e];
    const float p0 = __builtin_amdgcn_rcpf(1.f + __expf(-le0));
    const float p1 = __builtin_amdgcn_rcpf(1.f + __expf(-le1));
    rp0 += p0; rp1 += p1;
    const float psum = p0 + p1;
    const float gxf = x0f + (float)e;

    // csis: t = own-row delta (log2 domain). E shared by psig and softplus.
    const float t = (le1 - le0) * C_SH;
    const float E = exp2f(-fabsf(t));
    const float R = __builtin_amdgcn_rcpf(1.f + E);
    const float L = log2f(1.f + E);
    const float psig = (t >= 0.f ? E : 1.f) * R;   // sigmoid((le0-le1)/T)
    const float dorn = (b0[e] - b1[e]) * C_SH;     // next-row delta (cheap)
    rprod = fmaf(psig, dorn, rprod);
    rsp  += fmaxf(-t, 0.f) + L;                    // softplus2(own delta)

    float ap0 = p0, ap1 = p1, bp0 = p0, bp1 = p1;
    float d0sq = 0.f, d1sq = 0.f;
    if (N1) {
      const float dx1 = gxf - cx.t1x;
      d1sq = fmaf(dx1, dx1, dy1sq);
      const float art0 = (d1sq > cx.r11sq) ? 1.f : 0.f;
      ap0 = art0 * p0; ap1 = art0 * p1;
      const float a0p = ap0 + ap1;
      rA0 += a0p; rA0x = fmaf(gxf, a0p, rA0x);
      if (!N0) { rT00 += ap0; rT01 += ap1; }
    }
    if (N0) {
      const float dx0 = gxf - cx.t0x;
      d0sq = fmaf(dx0, dx0, dy0sq);
      const float art1 = (d0sq > cx.r01sq) ? 1.f : 0.f;
      bp0 = art1 * p0; bp1 = art1 * p1;
      const float a1p = bp0 + bp1;
      rA1 += a1p; rA1x = fmaf(gxf, a1p, rA1x);
      if (!N1) { rT10 += bp0; rT11 += bp1; }
    }
    if (!N0 || !N1) rpsx = fmaf(gxf, psum, rpsx);

    if (N0) {
      const float dist0 = __builtin_amdgcn_sqrtf(d0sq);
      const float elu0 = exp2f(fmaf(dist0, -cx.c00, LOG2E));
      const float eow0 = exp2f(fmaf(dist0, -cx.c01, LOG2E));
      acc[8]  = fmaf(fmaxf(1.f - elu0, 0.f), ap0, acc[8]);
      acc[9]  = fmaf(fmaxf(1.f - eow0, 0.f), ap1, acc[9]);
      acc[10] = fmaf(fmaxf(elu0 - 1.f, 0.f), 1.f - p0, acc[10]);
      acc[11] = fmaf(fmaxf(eow0 - 1.f, 0.f), 1.f - p1, acc[11]);
    }
    if (N1) {
      const float dist1 = __builtin_amdgcn_sqrtf(d1sq);
      const float elu1 = exp2f(fmaf(dist1, -cx.c10, LOG2E));
      const float eow1 = exp2f(fmaf(dist1, -cx.c11, LOG2E));
      acc[12] = fmaf(fmaxf(1.f - elu1, 0.f), bp0, acc[12]);
      acc[13] = fmaf(fmaxf(1.f - eow1, 0.f), bp1, acc[13]);
      acc[14] = fmaf(fmaxf(elu1 - 1.f, 0.f), 1.f - p0, acc[14]);
      acc[15] = fmaf(fmaxf(eow1 - 1.f, 0.f), 1.f - p1, acc[15]);
    }
  }
  // per-row fold (y factored out of the pixel loop)
  acc[6] += rp0; acc[7] += rp1; acc[16] += rprod; acc[17] += rsp;
  const float rps = rp0 + rp1;
  if (N1) { acc[0] += rA0; acc[1] = fmaf(yf, rA0, acc[1]); acc[2] += rA0x; }
  else    { acc[0] += rps; acc[1] = fmaf(yf, rps, acc[1]); acc[2] += rpsx; }
  if (N0) { acc[3] += rA1; acc[4] = fmaf(yf, rA1, acc[4]); acc[5] += rA1x; }
  else    { acc[3] += rps; acc[4] = fmaf(yf, rps, acc[4]); acc[5] += rpsx; }
  if (!N0) { acc[8]  += N1 ? rT00 : rp0; acc[9]  += N1 ? rT01 : rp1; }
  if (!N1) { acc[12] += N0 ? rT10 : rp0; acc[13] += N0 ? rT11 : rp1; }
}

#define DISPATCH_ROW(V0,V1,W0,W1,YF)                                       \
  { const bool nr0 = fabsf((YF) - cx.t0y) <= cut0;                         \
    const bool nr1 = fabsf((YF) - cx.t1y) <= cut1;                         \
    if (nr0) { if (nr1) do_row<true ,true >(V0,V1,W0,W1,YF,x0f,cx,acc);    \
               else     do_row<true ,false>(V0,V1,W0,W1,YF,x0f,cx,acc); }  \
    else     { if (nr1) do_row<false,true >(V0,V1,W0,W1,YF,x0f,cx,acc);    \
               else     do_row<false,false>(V0,V1,W0,W1,YF,x0f,cx,acc); } }

// ---------------- kernel 2: body + fused finalize ---------------------------
// 512 blocks x 1024 thr = 2 blocks/CU = 8 waves/SIMD. Block = (row, quarter),
// all 4 quarters + d,d+1 on one XCD (bid&7). Last block computes the scalar.
__global__ __launch_bounds__(1024) void k_body(const float* __restrict__ logits,
                                               const float* __restrict__ rad,
                                               Ws* __restrict__ ws,
                                               float* __restrict__ out)
{
  const int xcd  = blockIdx.x & 7;
  const int slot = blockIdx.x >> 3;          // 0..63
  const int row  = xcd * 16 + (slot >> 2);   // 16 consecutive rows per XCD
  const int quarter = slot & 3;
  const int tid  = threadIdx.x;
  const int lane = tid & 63;
  const int wid  = tid >> 6;           // 0..15
  const int b = row >> 6, d = row & 63;

  // combine scan halves in-register (12 broadcast loads, L2-hot)
  const int c0 = ws->scanp[row][0][0] + ws->scanp[row][1][0];
  const int c1 = ws->scanp[row][0][3] + ws->scanp[row][1][3];
  const float t0y = (c0 == 1) ? (float)(ws->scanp[row][0][1] + ws->scanp[row][1][1]) : -1.f;
  const float t0x = (c0 == 1) ? (float)(ws->scanp[row][0][2] + ws->scanp[row][1][2]) : -1.f;
  const float t1y = (c1 == 1) ? (float)(ws->scanp[row][0][4] + ws->scanp[row][1][4]) : -1.f;
  const float t1x = (c1 == 1) ? (float)(ws->scanp[row][0][5] + ws->scanp[row][1][5]) : -1.f;
  if (quarter == 0 && tid == 0) {
    ws->tgt[0][row][0] = t0y; ws->tgt[0][row][1] = t0x;
    ws->valid[0][row] = (c0 == 1) ? 1.f : 0.f;
    ws->tgt[1][row][0] = t1y; ws->tgt[1][row][1] = t1x;
    ws->valid[1][row] = (c1 == 1) ? 1.f : 0.f;
  }

  const float r00 = rad[0], r01 = rad[1], r10 = rad[2], r11 = rad[3];
  RowCtx cx;
  cx.t0y = t0y - EPSF; cx.t0x = t0x - EPSF;
  cx.t1y = t1y - EPSF; cx.t1x = t1x - EPSF;
  cx.r01sq = r01 * r01; cx.r11sq = r11 * r11;
  cx.c00 = LOG2E / r00; cx.c01 = LOG2E / r01;
  cx.c10 = LOG2E / r10; cx.c11 = LOG2E / r11;
  const float cut0 = 6.f * r01, cut1 = 6.f * r11;

  const float* l0 = logits + (((long long)(b * CC + 0) * DD + d) << 16);
  const float* l1 = logits + (((long long)(b * CC + 1) * DD + d) << 16);
  const bool csa = (d < DD - 2);             // csis product weight: d in [0,61]
  const bool csb = (d >= 1) && (d <= DD - 2);// softplus weight: d in [1,62]
  const long long noff = csa ? HW : 0;       // d>=62 re-reads own row, weight 0
  const float* m0 = l0 + noff;
  const float* m1 = l1 + noff;

  float acc[18];
#pragma unroll
  for (int i = 0; i < 18; ++i) acc[i] = 0.f;

  const float x0f = (float)(lane << 2);
  int y = quarter + (wid << 2);        // y == quarter (mod 4); 4 rows/wave
  int p = (y << 8) + (lane << 2);

  float4 v0 = *(const float4*)(l0 + p);
  float4 v1 = *(const float4*)(l1 + p);
  float4 w0 = *(const float4*)(m0 + p);
  float4 w1 = *(const float4*)(m1 + p);

#pragma unroll 1
  for (int j = 0; j < 3; ++j) {
    const int pn = p + 64 * 256;       // next row for this wave: y + 64
    float4 nv0 = *(const float4*)(l0 + pn);   // prefetch next iter
    float4 nv1 = *(const float4*)(l1 + pn);
    float4 nw0 = *(const float4*)(m0 + pn);
    float4 nw1 = *(const float4*)(m1 + pn);
    const float yf = (float)y;
    DISPATCH_ROW(v0, v1, w0, w1, yf);
    v0 = nv0; v1 = nv1; w0 = nw0; w1 = nw1; p = pn; y += 64;
  }
  { const float yf = (float)y;
    DISPATCH_ROW(v0, v1, w0, w1, yf); }

  // in-wave shuffle reduce -> per-wave partials in LDS -> 17 plain stores
  __shared__ float pl[16][18];
#pragma unroll
  for (int i = 0; i < 18; ++i) {
    float v = acc[i];
#pragma unroll
    for (int off = 32; off > 0; off >>= 1) v += __shfl_down(v, off, 64);
    if (lane == 0) pl[wid][i] = v;
  }
  __syncthreads();
  if (tid < 17) {
    float s;
    if (tid == 16) {
      float prod = 0.f, sp = 0.f;
#pragma unroll
      for (int w = 0; w < 16; ++w) { prod += pl[w][16]; sp += pl[w][17]; }
      s = (csa ? prod * LN2 : 0.f) - (csb ? sp * LN2 : 0.f);
    } else {
      s = 0.f;
#pragma unroll
      for (int w = 0; w < 16; ++w) s += pl[w][tid];
    }
    ws->part[row][quarter][tid] = s;
  }

  // ---- last-block retirement: fused finalize (no spin, count-based) ----
  __shared__ int isLast;
  __syncthreads();                       // part stores executed block-wide
  if (tid == 0) {
    __threadfence();                     // flush this block's stores (L2 wb)
    const int ticket = atomicAdd(&ws->done, 1);
    isLast = (ticket == 4 * NROW - 1) ? 1 : 0;
  }
  __syncthreads();
  if (isLast) {
    __threadfence();                     // acquire: see all blocks' parts
    const float PI = 3.14159265358979323846f;
    float cent = 0.f, cnst = 0.f, csis = 0.f;
    if (tid < NROW) {
      const int r = tid;
      float s[17];
#pragma unroll
      for (int i = 0; i < 17; ++i)
        s[i] = ws->part[r][0][i] + ws->part[r][1][i]
             + ws->part[r][2][i] + ws->part[r][3][i];
      const float P0 = s[6], P1 = s[7];
#pragma unroll
      for (int k = 0; k < 2; ++k) {
        const float vld = ws->valid[k][r];
        const float denom = s[3 * k + 0] + EPSF;
        const float yc = s[3 * k + 1] / denom;
        const float xc = s[3 * k + 2] / denom;
        const float dy = yc - ws->tgt[k][r][0] + EPSF;
        const float dx = xc - ws->tgt[k][r][1] + EPSF;
        cent += sqrtf(dy * dy + dx * dx) * vld;
        const float r_lu = rad[2 * k], r_ow = rad[2 * k + 1];
        const int o = 8 + 4 * k;
        cnst += (s[o]     / (ALPHAF * (P0 + EPSF)) +
                 s[o + 1] / (ALPHAF * (P1 + EPSF))) * vld
              + (s[o + 2] / (r_lu * r_lu * PI) +
                 s[o + 3] / (r_ow * r_ow * PI)) * vld;
      }
      csis = s[16];
    }
    // reduce 128 per-row values (waves 0,1) -> scalar
    __shared__ float fin[3][2];
#pragma unroll
    for (int off = 32; off > 0; off >>= 1) {
      cent += __shfl_down(cent, off, 64);
      cnst += __shfl_down(cnst, off, 64);
      csis += __shfl_down(csis, off, 64);
    }
    if (lane == 0 && wid < 2) { fin[0][wid] = cent; fin[1][wid] = cnst; fin[2][wid] = csis; }
    __syncthreads();
    if (tid == 0) {
      const float inv_rows = 1.0f / (float)NROW;
      const float loss_cent = (fin[0][0] + fin[0][1]) * inv_rows;
      const float loss_cnst = (fin[1][0] + fin[1][1]) * inv_rows;
      const float loss_csis = -(fin[2][0] + fin[2][1]) / (float)((long long)BB * (DD - 2) * HW);
      out[0] = 0.02f * loss_cent + loss_cnst + 0.001f * loss_csis;
    }
  }
}

// ---------------- launch -----------------------------------------------------
extern "C" void kernel_launch(void* const* d_in, const int* in_sizes, int n_in,
                              void* d_out, int out_size, void* d_ws, size_t ws_size,
                              hipStream_t stream) {
  const float* logits = (const float*)d_in[0];
  const int*   cl     = (const int*)d_in[1];
  const float* rad    = (const float*)d_in[2];
  Ws* ws = (Ws*)d_ws;

  hipMemsetAsync(d_ws, 0, sizeof(int), stream);   // zero retirement counter
  k_scan<<<2 * NROW, 1024, 0, stream>>>(cl, ws);
  k_body<<<4 * NROW, 1024, 0, stream>>>(logits, rad, ws, (float*)d_out);
}

// Round 19
// 37.322 us; speedup vs baseline: 1.5516x; 1.5516x over previous
//
#include <hip/hip_runtime.h>
#include <math.h>

#define BB 2
#define CC 2
#define DD 64
#define HW 65536
#define NROW 128
#define EPSF 1e-6f
#define ALPHAF 5.0f
#define LOG2E 1.44269504089f
#define LN2 0.69314718056f
#define INV_T (1.0f/0.7f)
#define C_SH (INV_T*LOG2E)

// R18 = R14 (best, 37.9us) + VALU micro-trims only. Structure frozen:
// 256 blocks x 1024thr fused scan+body, XCD row-grouping, depth-1 prefetch.
// Dead axes (measured): >4 waves/SIMD (R17: 2nd 1024-thr block never
// co-resident), depth-2 at 1024thr (R8-R10: 64-VGPR cap), spin-sync (R16),
// separate scan kernel (R12/R17: launch + amortization losses).
struct Ws {
  float tgt[2][NROW][2];
  float valid[2][NROW];
  float part[NROW][2][17];
  // 0 denom0 1 ynum0 2 xnum0 | 3 denom1 4 ynum1 5 xnum1 | 6 P0 7 P1
  // 8 SluOut0 9 SowOut0 10 SluIn0 11 SowIn0 | 12..15 same k=1 | 16 csis
};

// ---------------- row body ---------------------------------------------------
struct RowCtx {
  float t0y, t0x, t1y, t1x;   // target minus EPSF (so diff = g - t + EPS)
  float r01sq, r11sq;
  float c00, c01, c10, c11;   // LOG2E / r
};

// N0/N1: row within ring range of target0/1. Far: relu(1-exp(1-d/r))==1
// (err<=e^-5, validated absmax 0.0), relu(exp-1)==0, art==1 exactly.
// acc[16]=csis product sum (psig_own * delta_next), acc[17]=softplus_own sum.
// x-moment factoring: sum gxf*w = x0f*sum(w) + (w1 + 2*w2 + 3*w3).
template<bool N0, bool N1>
__device__ __forceinline__ void do_row(const float4& v0, const float4& v1,
                                       const float4& w0, const float4& w1,
                                       float yf, float x0f,
                                       const RowCtx& cx, float* acc)
{
  const float a0[4] = {v0.x, v0.y, v0.z, v0.w};
  const float a1[4] = {v1.x, v1.y, v1.z, v1.w};
  const float b0[4] = {w0.x, w0.y, w0.z, w0.w};
  const float b1[4] = {w1.x, w1.y, w1.z, w1.w};
  float rp0 = 0.f, rp1 = 0.f, rprod = 0.f, rsp = 0.f;
  float rpsE = 0.f;                       // sum e*psum_e (FF paths)
  float rA0 = 0.f, rA0x = 0.f, rT00 = 0.f, rT01 = 0.f;
  float rA1 = 0.f, rA1x = 0.f, rT10 = 0.f, rT11 = 0.f;
  const float dy0 = yf - cx.t0y;
  const float dy0sq = dy0 * dy0;
  const float dy1 = yf - cx.t1y;
  const float dy1sq = dy1 * dy1;
  float psume[4];
#pragma unroll
  for (int e = 0; e < 4; ++e) {
    const float le0 = a0[e], le1 = a1[e];
    const float p0 = __builtin_amdgcn_rcpf(1.f + __expf(-le0));
    const float p1 = __builtin_amdgcn_rcpf(1.f + __expf(-le1));
    rp0 += p0; rp1 += p1;
    const float psum = p0 + p1;
    psume[e] = psum;
    const float gxf = x0f + (float)e;

    // csis: t = own-row delta (log2 domain). E shared by psig and softplus.
    const float t = (le1 - le0) * C_SH;
    const float E = exp2f(-fabsf(t));
    const float R = __builtin_amdgcn_rcpf(1.f + E);
    const float L = log2f(1.f + E);
    const float psig = (t >= 0.f ? E : 1.f) * R;   // sigmoid((le0-le1)/T)
    const float dorn = (b0[e] - b1[e]) * C_SH;     // next-row delta (cheap)
    rprod = fmaf(psig, dorn, rprod);
    rsp  += fmaxf(-t, 0.f) + L;                    // softplus2(own delta)

    float ap0 = p0, ap1 = p1, bp0 = p0, bp1 = p1;
    float d0sq = 0.f, d1sq = 0.f;
    if (N1) {
      const float dx1 = gxf - cx.t1x;
      d1sq = fmaf(dx1, dx1, dy1sq);
      const float art0 = (d1sq > cx.r11sq) ? 1.f : 0.f;
      ap0 = art0 * p0; ap1 = art0 * p1;
      const float a0p = ap0 + ap1;
      rA0 += a0p; rA0x = fmaf(gxf, a0p, rA0x);
      if (!N0) { rT00 += ap0; rT01 += ap1; }
    }
    if (N0) {
      const float dx0 = gxf - cx.t0x;
      d0sq = fmaf(dx0, dx0, dy0sq);
      const float art1 = (d0sq > cx.r01sq) ? 1.f : 0.f;
      bp0 = art1 * p0; bp1 = art1 * p1;
      const float a1p = bp0 + bp1;
      rA1 += a1p; rA1x = fmaf(gxf, a1p, rA1x);
      if (!N1) { rT10 += bp0; rT11 += bp1; }
    }

    if (N0) {
      const float dist0 = __builtin_amdgcn_sqrtf(d0sq);
      const float elu0 = exp2f(fmaf(dist0, -cx.c00, LOG2E));
      const float eow0 = exp2f(fmaf(dist0, -cx.c01, LOG2E));
      acc[8]  = fmaf(fmaxf(1.f - elu0, 0.f), ap0, acc[8]);
      acc[9]  = fmaf(fmaxf(1.f - eow0, 0.f), ap1, acc[9]);
      acc[10] = fmaf(fmaxf(elu0 - 1.f, 0.f), 1.f - p0, acc[10]);
      acc[11] = fmaf(fmaxf(eow0 - 1.f, 0.f), 1.f - p1, acc[11]);
    }
    if (N1) {
      const float dist1 = __builtin_amdgcn_sqrtf(d1sq);
      const float elu1 = exp2f(fmaf(dist1, -cx.c10, LOG2E));
      const float eow1 = exp2f(fmaf(dist1, -cx.c11, LOG2E));
      acc[12] = fmaf(fmaxf(1.f - elu1, 0.f), bp0, acc[12]);
      acc[13] = fmaf(fmaxf(1.f - eow1, 0.f), bp1, acc[13]);
      acc[14] = fmaf(fmaxf(elu1 - 1.f, 0.f), 1.f - p0, acc[14]);
      acc[15] = fmaf(fmaxf(eow1 - 1.f, 0.f), 1.f - p1, acc[15]);
    }
  }
  // per-row fold (y and x0f factored out of the pixel loop)
  acc[6] += rp0; acc[7] += rp1; acc[16] += rprod; acc[17] += rsp;
  const float rps = rp0 + rp1;
  if (!N0 || !N1)
    rpsE = fmaf(3.f, psume[3], fmaf(2.f, psume[2], psume[1]));
  const float rpsx = fmaf(x0f, rps, rpsE);  // only valid on FF-ish paths
  if (N1) { acc[0] += rA0; acc[1] = fmaf(yf, rA0, acc[1]); acc[2] += rA0x; }
  else    { acc[0] += rps; acc[1] = fmaf(yf, rps, acc[1]); acc[2] += rpsx; }
  if (N0) { acc[3] += rA1; acc[4] = fmaf(yf, rA1, acc[4]); acc[5] += rA1x; }
  else    { acc[3] += rps; acc[4] = fmaf(yf, rps, acc[4]); acc[5] += rpsx; }
  if (!N0) { acc[8]  += N1 ? rT00 : rp0; acc[9]  += N1 ? rT01 : rp1; }
  if (!N1) { acc[12] += N0 ? rT10 : rp0; acc[13] += N0 ? rT11 : rp1; }
}

#define DISPATCH_ROW(V0,V1,W0,W1,YF)                                       \
  { const bool nr0 = fabsf((YF) - cx.t0y) <= cut0;                         \
    const bool nr1 = fabsf((YF) - cx.t1y) <= cut1;                         \
    if (nr0) { if (nr1) do_row<true ,true >(V0,V1,W0,W1,YF,x0f,cx,acc);    \
               else     do_row<true ,false>(V0,V1,W0,W1,YF,x0f,cx,acc); }  \
    else     { if (nr1) do_row<false,true >(V0,V1,W0,W1,YF,x0f,cx,acc);    \
               else     do_row<false,false>(V0,V1,W0,W1,YF,x0f,cx,acc); } }

// ---------------- fused kernel: scan + main ---------------------------------
// 256 blocks x 1024 threads. XCD remap: xcd=bid&7, each XCD owns 16
// consecutive rows (d,d+1 and sibling halves share that XCD's L2).
__global__ __launch_bounds__(1024) void k_all(const float* __restrict__ logits,
                                              const int* __restrict__ cl,
                                              const float* __restrict__ rad,
                                              Ws* __restrict__ ws)
{
  const int xcd  = blockIdx.x & 7;
  const int slot = blockIdx.x >> 3;          // 0..31
  const int row  = xcd * 16 + (slot >> 1);   // 16 consecutive rows per XCD
  const int half = slot & 1;
  const int tid  = threadIdx.x;
  const int lane = tid & 63;
  const int wid  = tid >> 6;           // 0..15
  const int b = row >> 6, d = row & 63;

  // body pointers + iter-0 loads issued BEFORE the scan (latency hides there)
  const float* l0 = logits + (((long long)(b * CC + 0) * DD + d) << 16);
  const float* l1 = logits + (((long long)(b * CC + 1) * DD + d) << 16);
  const bool csa = (d < DD - 2);             // csis product weight: d in [0,61]
  const bool csb = (d >= 1) && (d <= DD - 2);// softplus weight: d in [1,62]
  const long long noff = csa ? HW : 0;       // d>=62 re-reads own row, weight 0
  const float* m0 = l0 + noff;
  const float* m1 = l1 + noff;

  const float x0f = (float)(lane << 2);
  int y = half + (wid << 1);           // y == half (mod 2); 8 rows/wave, stride 32
  int p = (y << 8) + (lane << 2);

  float4 v0 = *(const float4*)(l0 + p);
  float4 v1 = *(const float4*)(l1 + p);
  float4 w0 = *(const float4*)(m0 + p);
  float4 w1 = *(const float4*)(m1 + p);

  // ---- phase 1: label scan over this row's 256 KB plane (2x int4 / iter) ----
  __shared__ int sacc[6];              // cnt0,ys0,xs0, cnt1,ys1,xs1
  if (tid < 6) sacc[tid] = 0;
  __syncthreads();
  {
    const int4* cp = (const int4*)(cl + ((long long)row << 16));
#pragma unroll 4
    for (int j = 0; j < 8; ++j) {
      const int i4a = tid + (j << 11);
      const int i4b = i4a + 1024;
      const int4 va = cp[i4a];
      const int4 vb = cp[i4b];
      if ((va.x | va.y | va.z | va.w) != 0) {
        const int vv[4] = {va.x, va.y, va.z, va.w};
#pragma unroll
        for (int e = 0; e < 4; ++e) {
          const int val = vv[e];
          if (val == 1 || val == 2) {
            const int hw = (i4a << 2) + e;
            const int k3 = (val - 1) * 3;
            atomicAdd(&sacc[k3 + 0], 1);
            atomicAdd(&sacc[k3 + 1], hw >> 8);
            atomicAdd(&sacc[k3 + 2], hw & 255);
          }
        }
      }
      if ((vb.x | vb.y | vb.z | vb.w) != 0) {
        const int vv[4] = {vb.x, vb.y, vb.z, vb.w};
#pragma unroll
        for (int e = 0; e < 4; ++e) {
          const int val = vv[e];
          if (val == 1 || val == 2) {
            const int hw = (i4b << 2) + e;
            const int k3 = (val - 1) * 3;
            atomicAdd(&sacc[k3 + 0], 1);
            atomicAdd(&sacc[k3 + 1], hw >> 8);
            atomicAdd(&sacc[k3 + 2], hw & 255);
          }
        }
      }
    }
  }
  __syncthreads();
  const int c0 = sacc[0], c1 = sacc[3];
  const float t0y = (c0 == 1) ? (float)sacc[1] : -1.f;
  const float t0x = (c0 == 1) ? (float)sacc[2] : -1.f;
  const float t1y = (c1 == 1) ? (float)sacc[4] : -1.f;
  const float t1x = (c1 == 1) ? (float)sacc[5] : -1.f;
  if (half == 0 && tid == 0) {
    ws->tgt[0][row][0] = t0y; ws->tgt[0][row][1] = t0x;
    ws->valid[0][row] = (c0 == 1) ? 1.f : 0.f;
    ws->tgt[1][row][0] = t1y; ws->tgt[1][row][1] = t1x;
    ws->valid[1][row] = (c1 == 1) ? 1.f : 0.f;
  }

  // ---- phase 2: fused loss body ----
  const float r00 = rad[0], r01 = rad[1], r10 = rad[2], r11 = rad[3];
  RowCtx cx;
  cx.t0y = t0y - EPSF; cx.t0x = t0x - EPSF;
  cx.t1y = t1y - EPSF; cx.t1x = t1x - EPSF;
  cx.r01sq = r01 * r01; cx.r11sq = r11 * r11;
  cx.c00 = LOG2E / r00; cx.c01 = LOG2E / r01;
  cx.c10 = LOG2E / r10; cx.c11 = LOG2E / r11;
  const float cut0 = 6.f * r01, cut1 = 6.f * r11;

  float acc[18];
#pragma unroll
  for (int i = 0; i < 18; ++i) acc[i] = 0.f;

#pragma unroll 1
  for (int j = 0; j < 7; ++j) {
    const int pn = p + 32 * 256;       // next row for this wave: y + 32
    float4 nv0 = *(const float4*)(l0 + pn);   // prefetch next iter
    float4 nv1 = *(const float4*)(l1 + pn);
    float4 nw0 = *(const float4*)(m0 + pn);
    float4 nw1 = *(const float4*)(m1 + pn);
    const float yf = (float)y;
    DISPATCH_ROW(v0, v1, w0, w1, yf);
    v0 = nv0; v1 = nv1; w0 = nw0; w1 = nw1; p = pn; y += 32;
  }
  { const float yf = (float)y;
    DISPATCH_ROW(v0, v1, w0, w1, yf); }

  // in-wave shuffle reduce -> per-wave partials in LDS -> 17 plain stores
  __shared__ float pl[16][18];
#pragma unroll
  for (int i = 0; i < 18; ++i) {
    float v = acc[i];
#pragma unroll
    for (int off = 32; off > 0; off >>= 1) v += __shfl_down(v, off, 64);
    if (lane == 0) pl[wid][i] = v;
  }
  __syncthreads();
  if (tid < 17) {
    float s;
    if (tid == 16) {
      float prod = 0.f, sp = 0.f;
#pragma unroll
      for (int w = 0; w < 16; ++w) { prod += pl[w][16]; sp += pl[w][17]; }
      s = (csa ? prod * LN2 : 0.f) - (csb ? sp * LN2 : 0.f);
    } else {
      s = 0.f;
#pragma unroll
      for (int w = 0; w < 16; ++w) s += pl[w][tid];
    }
    ws->part[row][half][tid] = s;
  }
}

// ---------------- finalize ---------------------------------------------------
__global__ void k_final(const float* __restrict__ rad,
                        const Ws* __restrict__ ws, float* __restrict__ out) {
  __shared__ float red[3][NROW];
  const int r = threadIdx.x;
  const float PI = 3.14159265358979323846f;
  float cent = 0.0f, cnst = 0.0f, csis = 0.0f;
  if (r < NROW) {
    float s[17];
#pragma unroll
    for (int i = 0; i < 17; ++i)
      s[i] = ws->part[r][0][i] + ws->part[r][1][i];

    const float P0 = s[6], P1 = s[7];
#pragma unroll
    for (int k = 0; k < 2; ++k) {
      const float vld = ws->valid[k][r];
      const float denom = s[3 * k + 0] + EPSF;
      const float yc = s[3 * k + 1] / denom;
      const float xc = s[3 * k + 2] / denom;
      const float dy = yc - ws->tgt[k][r][0] + EPSF;
      const float dx = xc - ws->tgt[k][r][1] + EPSF;
      cent += sqrtf(dy * dy + dx * dx) * vld;
      const float r_lu = rad[2 * k], r_ow = rad[2 * k + 1];
      const int o = 8 + 4 * k;
      const float rc_out = (s[o]     / (ALPHAF * (P0 + EPSF)) +
                            s[o + 1] / (ALPHAF * (P1 + EPSF))) * vld;
      const float rc_in  = (s[o + 2] / (r_lu * r_lu * PI) +
                            s[o + 3] / (r_ow * r_ow * PI)) * vld;
      cnst += rc_out + rc_in;
    }
    csis = s[16];
  }
  red[0][r] = cent; red[1][r] = cnst; red[2][r] = csis;
  __syncthreads();
  for (int st = NROW / 2; st > 0; st >>= 1) {
    if (r < st) {
      red[0][r] += red[0][r + st];
      red[1][r] += red[1][r + st];
      red[2][r] += red[2][r + st];
    }
    __syncthreads();
  }
  if (r == 0) {
    const float inv_rows = 1.0f / (float)NROW;
    const float loss_cent = red[0][0] * inv_rows;
    const float loss_cnst = red[1][0] * inv_rows;
    const float loss_csis = -red[2][0] / (float)((long long)BB * (DD - 2) * HW);
    out[0] = 0.02f * loss_cent + loss_cnst + 0.001f * loss_csis;
  }
}

// ---------------- launch -----------------------------------------------------
extern "C" void kernel_launch(void* const* d_in, const int* in_sizes, int n_in,
                              void* d_out, int out_size, void* d_ws, size_t ws_size,
                              hipStream_t stream) {
  const float* logits = (const float*)d_in[0];
  const int*   cl     = (const int*)d_in[1];
  const float* rad    = (const float*)d_in[2];
  Ws* ws = (Ws*)d_ws;

  k_all<<<2 * NROW, 1024, 0, stream>>>(logits, cl, rad, ws);
  k_final<<<1, NROW, 0, stream>>>(rad, ws, (float*)d_out);
}